// Round 13
// baseline (748.524 us; speedup 1.0000x reference)
//
#include <hip/hip_runtime.h>
#include <cstdint>
#include <cstddef>

#define B_ 2048
#define N_ 256

typedef unsigned short u16;
typedef unsigned int u32;
typedef __attribute__((ext_vector_type(8))) short short8;
typedef __attribute__((ext_vector_type(4))) float floatx4;

__device__ __forceinline__ u16 f2bf(float f) {
  union { float f; unsigned u; } v; v.f = f;
  unsigned u = v.u;
  return (u16)((u + 0x7FFFu + ((u >> 16) & 1u)) >> 16);
}
__device__ __forceinline__ u32 cvt_pk_bf16(float a, float b) {
  u32 r;
  asm("v_cvt_pk_bf16_f32 %0, %1, %2" : "=v"(r) : "v"(a), "v"(b));
  return r;
}
// VALU butterfly adds over lane^16 / lane^32 (proven bit-exact R8)
__device__ __forceinline__ float bfly16(float x) {
  auto r = __builtin_amdgcn_permlane16_swap(__float_as_int(x), __float_as_int(x), false, false);
  return __int_as_float(r[0]) + __int_as_float(r[1]);
}
__device__ __forceinline__ float bfly32(float x) {
  auto r = __builtin_amdgcn_permlane32_swap(__float_as_int(x), __float_as_int(x), false, false);
  return __int_as_float(r[0]) + __int_as_float(r[1]);
}
#define CC_ 2.885390081777927f  /* 2*log2(e) */
__device__ __forceinline__ float tanh_fast(float x) {
  float u = __builtin_amdgcn_exp2f(x * CC_);
  return fmaf(__builtin_amdgcn_rcpf(u + 1.0f), -2.0f, 1.0f);
}
__device__ __forceinline__ float tanh_arg(float x) {  // tanh(y) where x = y*CC_ already
  float u = __builtin_amdgcn_exp2f(x);
  return fmaf(__builtin_amdgcn_rcpf(u + 1.0f), -2.0f, 1.0f);
}
__device__ __forceinline__ float four_emb(float tv, int j) {
  if (j == 0) return tv;
  int jj = (j <= 8) ? j : j - 8;
  float sc = __int_as_float((jj + 125) << 23);  // 2^(jj-2)
  float r = __builtin_amdgcn_fractf(tv * sc);
  return (j <= 8) ? __builtin_amdgcn_sinf(r) : __builtin_amdgcn_cosf(r);
}
__device__ __forceinline__ void bar_lgkm() {
  asm volatile("s_waitcnt lgkmcnt(0)" ::: "memory");
  __builtin_amdgcn_s_barrier();
  __builtin_amdgcn_sched_barrier(0);
}

// ---------------- combined weight packer (one launch).
__global__ void rlp_pack_all(const float* __restrict__ dw0, const float* __restrict__ dw1,
                             const float* __restrict__ dw2, const float* __restrict__ dw3,
                             const float* __restrict__ ew0, const float* __restrict__ ew1,
                             const float* __restrict__ ew2, const float* __restrict__ ew3,
                             u16* __restrict__ wdyn, u16* __restrict__ wdec) {
  int e = blockIdx.x * blockDim.x + threadIdx.x;
  const float* W; int K, Nc, ks, base; u16* dst;
  if (e < 20480)       { W = dw0; K = 145; Nc = 128; ks = 5; dst = wdyn;         base = 0; }
  else if (e < 36864)  { W = dw1; K = 128; Nc = 128; ks = 4; dst = wdyn + 20480; base = 20480; }
  else if (e < 53248)  { W = dw2; K = 128; Nc = 128; ks = 4; dst = wdyn + 36864; base = 36864; }
  else if (e < 61440)  { W = dw3; K = 128; Nc = 64;  ks = 4; dst = wdyn + 53248; base = 53248; }
  else if (e < 69632)  { W = ew0; K = 64;  Nc = 128; ks = 2; dst = wdec;         base = 61440; }
  else if (e < 86016)  { W = ew1; K = 128; Nc = 128; ks = 4; dst = wdec + 8192;  base = 69632; }
  else if (e < 102400) { W = ew2; K = 128; Nc = 128; ks = 4; dst = wdec + 24576; base = 86016; }
  else if (e < 104448) { W = ew3; K = 128; Nc = 14;  ks = 4; dst = wdec + 40960; base = 102400; }
  else return;
  int el = e - base;
  int j = el & 7;
  int lane = (el >> 3) & 63;
  int tt = el >> 9;
  int ksi = tt % ks;
  int nt = tt / ks;
  int col = nt * 16 + (lane & 15);
  int k = ksi * 32 + ((lane >> 4) << 3) + j;
  float v = 0.0f;
  if (k < K && col < Nc) v = W[k * Nc + col];
  dst[el] = f2bf(v);
}

// ---------------- one hidden layer, ONE 16-col tile per wave (16-wave version).
// Lane (g, rrow): acc cols = 16wl + 4g + 0..3; finalize half-split by tsel=rrow>>3
// -> each lane tanh-finalizes 2 cols at wofs. 2 lgkm barriers (shared by all phases).
template <int KS>
__device__ __forceinline__ void mlp_layer1t(
    const short8* wT, floatx4 bv, float2 Ap, float2 Ep,
    const u16* src, u16* dst, float* lnbuf,
    int grpoff, int wl, int lane, int tsel, int wofs) {
  const int rrow = lane & 15;
  const int g = lane >> 4;
  const int srow = rrow & 7;
  short8 xf[KS];
#pragma unroll
  for (int ks = 0; ks < KS; ks++)
    xf[ks] = *reinterpret_cast<const short8*>(&src[srow * 168 + ks * 32 + g * 8]);
  floatx4 acc = bv;
#pragma unroll
  for (int ks = 0; ks < KS; ks++)
    acc = __builtin_amdgcn_mfma_f32_16x16x32_bf16(wT[ks], xf[ks], acc, 0, 0, 0);
  float s = (acc[0] + acc[1]) + (acc[2] + acc[3]);
  float q = (acc[0] * acc[0] + acc[1] * acc[1]) + (acc[2] * acc[2] + acc[3] * acc[3]);
  s = bfly32(bfly16(s));          // sum over the wave's 4 g-groups (16 cols)
  q = bfly32(bfly16(q));
  // lanes 0-7 (g=0) hold rows 0-7; slot = grpoff + 2*wl (16 slots/row: dyn 0-15, dec 16-31)
  if (lane < 8)
    *reinterpret_cast<float2*>(&lnbuf[lane * 36 + grpoff + 2 * wl]) = make_float2(s, q);
  bar_lgkm();
  floatx4 p0 = *reinterpret_cast<const floatx4*>(&lnbuf[srow * 36 + grpoff + 0]);
  floatx4 p1 = *reinterpret_cast<const floatx4*>(&lnbuf[srow * 36 + grpoff + 4]);
  floatx4 p2 = *reinterpret_cast<const floatx4*>(&lnbuf[srow * 36 + grpoff + 8]);
  floatx4 p3 = *reinterpret_cast<const floatx4*>(&lnbuf[srow * 36 + grpoff + 12]);
  float S = ((p0[0] + p0[2]) + (p1[0] + p1[2])) + ((p2[0] + p2[2]) + (p3[0] + p3[2]));
  float Q = ((p0[1] + p0[3]) + (p1[1] + p1[3])) + ((p2[1] + p2[3]) + (p3[1] + p3[3]));
  float mean = S * 0.0078125f;
  float rs = __builtin_amdgcn_rsqf(fmaf(Q, 0.0078125f, -mean * mean) + 1e-5f);
  float v0 = tsel ? acc[2] : acc[0];
  float v1 = tsel ? acc[3] : acc[1];
  float a0 = fmaf((v0 - mean) * rs, Ap.x, Ep.x);
  float a1 = fmaf((v1 - mean) * rs, Ap.y, Ep.y);
  *reinterpret_cast<u32*>(&dst[srow * 168 + wofs]) = cvt_pk_bf16(tanh_arg(a0), tanh_arg(a1));
  bar_lgkm();
}

// ---------------- fused scan+decode, 16 waves (4/SIMD): waves 0-7 dynamics (tile wl),
// waves 8-15 decoder (tile wl). 8 rows/WG, grid 256. L4 weights staged in LDS.
__global__ __launch_bounds__(1024, 1) void rlp_fused5(
    const float* __restrict__ t,
    const u16* __restrict__ wdyn, const u16* __restrict__ wdec,
    const float* __restrict__ ctxg, const float* __restrict__ cew,
    const float* __restrict__ ceb, const float* __restrict__ z0w,
    const float* __restrict__ z0b,
    const float* __restrict__ db0, const float* __restrict__ db1,
    const float* __restrict__ db2, const float* __restrict__ db3,
    const float* __restrict__ dg0, const float* __restrict__ dbe0,
    const float* __restrict__ dg1, const float* __restrict__ dbe1,
    const float* __restrict__ dg2, const float* __restrict__ dbe2,
    const float* __restrict__ eb0, const float* __restrict__ eb1,
    const float* __restrict__ eb2, const float* __restrict__ eb3,
    const float* __restrict__ eg0, const float* __restrict__ ebe0,
    const float* __restrict__ eg1, const float* __restrict__ ebe1,
    const float* __restrict__ eg2, const float* __restrict__ ebe2,
    float* __restrict__ out) {
  __shared__ __align__(16) u16 xb[8 * 168];   // 0-63 z | 64-80 temb | 81-144 ctx | 145-167 zero
  __shared__ __align__(16) u16 hdA[8 * 168];
  __shared__ __align__(16) u16 hdB[8 * 168];
  __shared__ __align__(16) u16 heA[8 * 168];
  __shared__ __align__(16) u16 heB[8 * 168];
  __shared__ __align__(16) float lnS[8 * 36];  // [row][dyn slots 0-15 | dec slots 16-31]
  __shared__ __align__(16) float tl[8][260];
  __shared__ __align__(16) u16 w4d[8192];      // dyn L4 frag blob (LDS copy)
  __shared__ __align__(16) u16 w4e[2048];      // dec L4 frag blob
  __shared__ float ctxe[8][64];
  __shared__ float zbuf[8][64];

  const int tid = threadIdx.x;
  const int wv = tid >> 6;
  const int lane = tid & 63;
  const int rrow = lane & 15;
  const int g = lane >> 4;
  const int r8 = rrow & 7;
  const int tsel = rrow >> 3;
  const int wl = wv & 7;
  const bool isdyn = (wv < 8);
  const int grpoff = isdyn ? 0 : 16;
  const int gb = blockIdx.x * 8;
  const int c0 = 16 * wl + 4 * g;
  const int wofs = c0 + 2 * tsel;            // this lane's finalize col pair

  const float* pb1 = isdyn ? db0 : eb0;
  const float* pg1 = isdyn ? dg0 : eg0;
  const float* pe1 = isdyn ? dbe0 : ebe0;
  const float* pb2 = isdyn ? db1 : eb1;
  const float* pg2 = isdyn ? dg1 : eg1;
  const float* pe2 = isdyn ? dbe1 : ebe1;
  const float* pb3 = isdyn ? db2 : eb2;
  const float* pg3 = isdyn ? dg2 : eg2;
  const float* pe3 = isdyn ? dbe2 : ebe2;

  const floatx4 b1 = *(const floatx4*)&pb1[c0];
  const floatx4 b2 = *(const floatx4*)&pb2[c0];
  const floatx4 b3 = *(const floatx4*)&pb3[c0];
  const float2 A1 = make_float2(pg1[wofs] * CC_, pg1[wofs + 1] * CC_);
  const float2 E1 = make_float2(pe1[wofs] * CC_, pe1[wofs + 1] * CC_);
  const float2 A2 = make_float2(pg2[wofs] * CC_, pg2[wofs + 1] * CC_);
  const float2 E2 = make_float2(pe2[wofs] * CC_, pe2[wofs + 1] * CC_);
  const float2 A3 = make_float2(pg3[wofs] * CC_, pg3[wofs + 1] * CC_);
  const float2 E3 = make_float2(pe3[wofs] * CC_, pe3[wofs + 1] * CC_);
  floatx4 b4 = {0.0f, 0.0f, 0.0f, 0.0f};
  if (isdyn) {
    if (wl < 4) b4 = *(const floatx4*)&db3[16 * wl + 4 * g];
  } else if (wv == 8) {
    int cb = 4 * g;
    b4[0] = (cb + 0 < 14) ? eb3[cb + 0] : 0.0f;
    b4[1] = (cb + 1 < 14) ? eb3[cb + 1] : 0.0f;
    b4[2] = (cb + 2 < 14) ? eb3[cb + 2] : 0.0f;
    b4[3] = (cb + 3 < 14) ? eb3[cb + 3] : 0.0f;
  }

  // ---- weight fragments (single tile wl): slots [0-4]=L1, [5-8]=L2, [9-12]=L3.
  short8 wA[13];
  if (isdyn) {
#pragma unroll
    for (int ks = 0; ks < 5; ks++)
      wA[ks] = *(const short8*)(wdyn + ((size_t)(wl * 5 + ks) * 64 + lane) * 8);
#pragma unroll
    for (int ks = 0; ks < 4; ks++) {
      wA[5 + ks] = *(const short8*)(wdyn + 20480 + ((size_t)(wl * 4 + ks) * 64 + lane) * 8);
      wA[9 + ks] = *(const short8*)(wdyn + 36864 + ((size_t)(wl * 4 + ks) * 64 + lane) * 8);
    }
  } else {
#pragma unroll
    for (int ks = 0; ks < 2; ks++)
      wA[ks] = *(const short8*)(wdec + ((size_t)(wl * 2 + ks) * 64 + lane) * 8);
    wA[2] = wA[0]; wA[3] = wA[0]; wA[4] = wA[0];
#pragma unroll
    for (int ks = 0; ks < 4; ks++) {
      wA[5 + ks] = *(const short8*)(wdec + 8192 + ((size_t)(wl * 4 + ks) * 64 + lane) * 8);
      wA[9 + ks] = *(const short8*)(wdec + 24576 + ((size_t)(wl * 4 + ks) * 64 + lane) * 8);
    }
  }
  u16* h0 = isdyn ? hdA : heA;
  u16* h1 = isdyn ? hdB : heB;

  // ---- prologue: t + L4 blobs -> LDS, zero xb, ctx encoder, z0 encoder, temb(0)
  for (int i = tid; i < 8 * 256; i += 1024) {
    int r = i >> 8, c = i & 255;
    tl[r][c] = t[(size_t)(gb + r) * N_ + c];
  }
  for (int i = tid; i < 8192 / 8; i += 1024)
    reinterpret_cast<uint4*>(w4d)[i] = reinterpret_cast<const uint4*>(wdyn + 53248)[i];
  for (int i = tid; i < 2048 / 8; i += 1024)
    reinterpret_cast<uint4*>(w4e)[i] = reinterpret_cast<const uint4*>(wdec + 40960)[i];
  for (int i = tid; i < 8 * 168 / 2; i += 1024) reinterpret_cast<u32*>(&xb[0])[i] = 0;
  __syncthreads();
  if (tid < 512) {
    int b = tid >> 6, c = tid & 63;
    float s = ceb[c];
#pragma unroll
    for (int k = 0; k < 32; k++) s += ctxg[(size_t)(gb + b) * 32 + k] * cew[k * 64 + c];
    float v = tanh_fast(s);
    ctxe[b][c] = v;
    xb[b * 168 + 81 + c] = f2bf(v);
  }
  __syncthreads();
  if (tid < 512) {
    int b = tid >> 6, l = tid & 63;
    float s = z0b[l];
#pragma unroll 8
    for (int k = 0; k < 64; k++) s += ctxe[b][k] * z0w[k * 64 + l];
    zbuf[b][l] = tanh_fast(s);
  }
  if (tid < 136) {
    int b = tid / 17, j = tid - b * 17;
    xb[b * 168 + 64 + j] = f2bf(four_emb(tl[b][0], j));
  }
  __syncthreads();

  // z0 into dyn registers (waves 0-3 hold z cols 16wl+4g..+3) + xb
  float zr0 = 0.0f, zr1 = 0.0f, zr2 = 0.0f, zr3 = 0.0f;
  if (isdyn && wl < 4) {
    const floatx4 zv = *(const floatx4*)&zbuf[r8][16 * wl + 4 * g];
    zr0 = zv[0]; zr1 = zv[1]; zr2 = zv[2]; zr3 = zv[3];
    if (rrow < 8) {
      *reinterpret_cast<uint2*>(&xb[rrow * 168 + 16 * wl + 4 * g]) =
          make_uint2(cvt_pk_bf16(zr0, zr1), cvt_pk_bf16(zr2, zr3));
    }
  }
  __syncthreads();

  // per-lane output row pointer (dec L4, wave 8)
  float* po = out + ((size_t)(gb + r8) * N_) * 14 + 4 * g;

  for (int n = 0; n < N_; n++) {
    // phase A: L1 (dyn K=160 -> 5 frags from xb; dec K=64 -> 2 frags of z)
    if (isdyn)
      mlp_layer1t<5>(wA, b1, A1, E1, xb, h0, lnS, grpoff, wl, lane, tsel, wofs);
    else
      mlp_layer1t<2>(wA, b1, A1, E1, xb, h0, lnS, grpoff, wl, lane, tsel, wofs);
    // phase B: L2 ; phase C: L3
    mlp_layer1t<4>(wA + 5, b2, A2, E2, h0, h1, lnS, grpoff, wl, lane, tsel, wofs);
    mlp_layer1t<4>(wA + 9, b3, A3, E3, h1, h0, lnS, grpoff, wl, lane, tsel, wofs);
    // phase D
    if (isdyn) {
      if (wl < 4 && n < N_ - 1) {
        short8 xf4[4], w4t[4];
#pragma unroll
        for (int ks = 0; ks < 4; ks++) {
          xf4[ks] = *reinterpret_cast<const short8*>(&h0[r8 * 168 + ks * 32 + g * 8]);
          w4t[ks] = *reinterpret_cast<const short8*>(&w4d[((size_t)(wl * 4 + ks) * 64 + lane) * 8]);
        }
        floatx4 da = b4;
#pragma unroll
        for (int ks = 0; ks < 4; ks++)
          da = __builtin_amdgcn_mfma_f32_16x16x32_bf16(w4t[ks], xf4[ks], da, 0, 0, 0);
        float dt = tl[r8][n + 1] - tl[r8][n];
        zr0 += dt * da[0]; zr1 += dt * da[1]; zr2 += dt * da[2]; zr3 += dt * da[3];
        if (rrow < 8) {
          *reinterpret_cast<uint2*>(&xb[rrow * 168 + 16 * wl + 4 * g]) =
              make_uint2(cvt_pk_bf16(zr0, zr1), cvt_pk_bf16(zr2, zr3));
        }
      }
    } else if (wv == 8) {
      // decoder L4: 14 output cols for the 8 rows, step n
      short8 xf4[4], w4t[4];
#pragma unroll
      for (int ks = 0; ks < 4; ks++) {
        xf4[ks] = *reinterpret_cast<const short8*>(&h0[r8 * 168 + ks * 32 + g * 8]);
        w4t[ks] = *reinterpret_cast<const short8*>(&w4e[((size_t)ks * 64 + lane) * 8]);
      }
      floatx4 da = b4;
#pragma unroll
      for (int ks = 0; ks < 4; ks++)
        da = __builtin_amdgcn_mfma_f32_16x16x32_bf16(w4t[ks], xf4[ks], da, 0, 0, 0);
      if (rrow < 8) {
        float* p = po + (size_t)n * 14;
        *reinterpret_cast<float2*>(p) = make_float2(da[0], da[1]);
        if (g < 3) *reinterpret_cast<float2*>(p + 2) = make_float2(da[2], da[3]);
      }
    } else if (wv >= 12) {
      // waves 12-15: Fourier embedding for step n+1
      int t2 = tid - 768;
      if (t2 < 136 && n < N_ - 2) {
        int b = t2 / 17, j = t2 - b * 17;
        xb[b * 168 + 64 + j] = f2bf(four_emb(tl[b][n + 1], j));
      }
    }
    bar_lgkm();
  }
}

extern "C" void kernel_launch(void* const* d_in, const int* in_sizes, int n_in,
                              void* d_out, int out_size, void* d_ws, size_t ws_size,
                              hipStream_t stream) {
  const float* t = (const float*)d_in[0];
  const float* ctx = (const float*)d_in[1];
  const float* ce_w = (const float*)d_in[2];
  const float* ce_b = (const float*)d_in[3];
  const float* z0_w = (const float*)d_in[4];
  const float* z0_b = (const float*)d_in[5];
  const float* dw0 = (const float*)d_in[6];
  const float* db0 = (const float*)d_in[7];
  const float* dw1 = (const float*)d_in[8];
  const float* db1 = (const float*)d_in[9];
  const float* dw2 = (const float*)d_in[10];
  const float* db2 = (const float*)d_in[11];
  const float* dw3 = (const float*)d_in[12];
  const float* db3 = (const float*)d_in[13];
  const float* dg0 = (const float*)d_in[14];
  const float* dbe0 = (const float*)d_in[15];
  const float* dg1 = (const float*)d_in[16];
  const float* dbe1 = (const float*)d_in[17];
  const float* dg2 = (const float*)d_in[18];
  const float* dbe2 = (const float*)d_in[19];
  const float* ew0 = (const float*)d_in[20];
  const float* eb0 = (const float*)d_in[21];
  const float* ew1 = (const float*)d_in[22];
  const float* eb1 = (const float*)d_in[23];
  const float* ew2 = (const float*)d_in[24];
  const float* eb2 = (const float*)d_in[25];
  const float* ew3 = (const float*)d_in[26];
  const float* eb3 = (const float*)d_in[27];
  const float* eg0 = (const float*)d_in[28];
  const float* ebe0 = (const float*)d_in[29];
  const float* eg1 = (const float*)d_in[30];
  const float* ebe1 = (const float*)d_in[31];
  const float* eg2 = (const float*)d_in[32];
  const float* ebe2 = (const float*)d_in[33];
  float* out = (float*)d_out;

  char* ws = (char*)d_ws;
  u16* wdyn = (u16*)(ws + 0);        // 61440 elems = 122880 B
  u16* wdec = (u16*)(ws + 122880);   // 43008 elems =  86016 B

  rlp_pack_all<<<408, 256, 0, stream>>>(dw0, dw1, dw2, dw3, ew0, ew1, ew2, ew3, wdyn, wdec);

  rlp_fused5<<<B_ / 8, 1024, 0, stream>>>(t, wdyn, wdec, ctx, ce_w, ce_b, z0_w, z0_b,
      db0, db1, db2, db3, dg0, dbe0, dg1, dbe1, dg2, dbe2,
      eb0, eb1, eb2, eb3, eg0, ebe0, eg1, ebe1, eg2, ebe2, out);
}

// Round 14
// 463.943 us; speedup vs baseline: 1.6134x; 1.6134x over previous
//
#include <hip/hip_runtime.h>
#include <cstdint>
#include <cstddef>

#define B_ 2048
#define N_ 256

typedef unsigned short u16;
typedef unsigned int u32;
typedef __attribute__((ext_vector_type(8))) short short8;
typedef __attribute__((ext_vector_type(4))) float floatx4;

__device__ __forceinline__ u16 f2bf(float f) {
  union { float f; unsigned u; } v; v.f = f;
  unsigned u = v.u;
  return (u16)((u + 0x7FFFu + ((u >> 16) & 1u)) >> 16);
}
__device__ __forceinline__ u32 cvt_pk_bf16(float a, float b) {
  u32 r;
  asm("v_cvt_pk_bf16_f32 %0, %1, %2" : "=v"(r) : "v"(a), "v"(b));
  return r;
}
// VALU butterfly adds over lane^16 / lane^32 (proven bit-exact R8)
__device__ __forceinline__ float bfly16(float x) {
  auto r = __builtin_amdgcn_permlane16_swap(__float_as_int(x), __float_as_int(x), false, false);
  return __int_as_float(r[0]) + __int_as_float(r[1]);
}
__device__ __forceinline__ float bfly32(float x) {
  auto r = __builtin_amdgcn_permlane32_swap(__float_as_int(x), __float_as_int(x), false, false);
  return __int_as_float(r[0]) + __int_as_float(r[1]);
}
#define CC_ 2.885390081777927f  /* 2*log2(e) */
__device__ __forceinline__ float tanh_fast(float x) {
  float u = __builtin_amdgcn_exp2f(x * CC_);
  return fmaf(__builtin_amdgcn_rcpf(u + 1.0f), -2.0f, 1.0f);
}
__device__ __forceinline__ float tanh_arg(float x) {  // tanh(y) where x = y*CC_ already
  float u = __builtin_amdgcn_exp2f(x);
  return fmaf(__builtin_amdgcn_rcpf(u + 1.0f), -2.0f, 1.0f);
}
__device__ __forceinline__ float four_emb(float tv, int j) {
  if (j == 0) return tv;
  int jj = (j <= 8) ? j : j - 8;
  float sc = __int_as_float((jj + 125) << 23);  // 2^(jj-2)
  float r = __builtin_amdgcn_fractf(tv * sc);
  return (j <= 8) ? __builtin_amdgcn_sinf(r) : __builtin_amdgcn_cosf(r);
}
// LDS-only barrier (no vmcnt drain). sched_barrier removed: compiler tracks its own
// ds_read->use deps; "memory" clobber already pins LDS op order across the barrier.
__device__ __forceinline__ void bar_lgkm() {
  asm volatile("s_waitcnt lgkmcnt(0)" ::: "memory");
  __builtin_amdgcn_s_barrier();
}

// ---------------- combined weight packer (one launch).
__global__ void rlp_pack_all(const float* __restrict__ dw0, const float* __restrict__ dw1,
                             const float* __restrict__ dw2, const float* __restrict__ dw3,
                             const float* __restrict__ ew0, const float* __restrict__ ew1,
                             const float* __restrict__ ew2, const float* __restrict__ ew3,
                             u16* __restrict__ wdyn, u16* __restrict__ wdec) {
  int e = blockIdx.x * blockDim.x + threadIdx.x;
  const float* W; int K, Nc, ks, base; u16* dst;
  if (e < 20480)       { W = dw0; K = 145; Nc = 128; ks = 5; dst = wdyn;         base = 0; }
  else if (e < 36864)  { W = dw1; K = 128; Nc = 128; ks = 4; dst = wdyn + 20480; base = 20480; }
  else if (e < 53248)  { W = dw2; K = 128; Nc = 128; ks = 4; dst = wdyn + 36864; base = 36864; }
  else if (e < 61440)  { W = dw3; K = 128; Nc = 64;  ks = 4; dst = wdyn + 53248; base = 53248; }
  else if (e < 69632)  { W = ew0; K = 64;  Nc = 128; ks = 2; dst = wdec;         base = 61440; }
  else if (e < 86016)  { W = ew1; K = 128; Nc = 128; ks = 4; dst = wdec + 8192;  base = 69632; }
  else if (e < 102400) { W = ew2; K = 128; Nc = 128; ks = 4; dst = wdec + 24576; base = 86016; }
  else if (e < 104448) { W = ew3; K = 128; Nc = 14;  ks = 4; dst = wdec + 40960; base = 102400; }
  else return;
  int el = e - base;
  int j = el & 7;
  int lane = (el >> 3) & 63;
  int tt = el >> 9;
  int ksi = tt % ks;
  int nt = tt / ks;
  int col = nt * 16 + (lane & 15);
  int k = ksi * 32 + ((lane >> 4) << 3) + j;
  float v = 0.0f;
  if (k < K && col < Nc) v = W[k * Nc + col];
  dst[el] = f2bf(v);
}

// ---------------- one hidden layer, 2 col-tiles per wave (R12 structure).
// Lane-split finalize: lanes rrow<8 finalize tile0, rrow>=8 finalize tile1.
template <int KS, int KSD>
__device__ __forceinline__ void mlp_layer2(
    const short8* wT0, const short8* wT1, const short8* xstat,
    floatx4 bv0, floatx4 bv1,
    floatx4 Asel, floatx4 Esel,       // per-lane consts at cols [wofs..wofs+3]
    const u16* src, u16* dst, float* lnbuf,
    int grpoff, int wl, int lane, int tsel, int wofs) {
  const int rrow = lane & 15;
  const int g = lane >> 4;
  const int srow = rrow & 7;
  short8 xf[KSD];
#pragma unroll
  for (int ks = 0; ks < KSD; ks++)
    xf[ks] = *reinterpret_cast<const short8*>(&src[srow * 168 + ks * 32 + g * 8]);
  floatx4 acc0 = bv0, acc1 = bv1;
  __builtin_amdgcn_s_setprio(1);
#pragma unroll
  for (int ks = 0; ks < KSD; ks++) {
    acc0 = __builtin_amdgcn_mfma_f32_16x16x32_bf16(wT0[ks], xf[ks], acc0, 0, 0, 0);
    acc1 = __builtin_amdgcn_mfma_f32_16x16x32_bf16(wT1[ks], xf[ks], acc1, 0, 0, 0);
  }
#pragma unroll
  for (int ks = KSD; ks < KS; ks++) {
    acc0 = __builtin_amdgcn_mfma_f32_16x16x32_bf16(wT0[ks], xstat[ks - KSD], acc0, 0, 0, 0);
    acc1 = __builtin_amdgcn_mfma_f32_16x16x32_bf16(wT1[ks], xstat[ks - KSD], acc1, 0, 0, 0);
  }
  __builtin_amdgcn_s_setprio(0);
  float s = ((acc0[0] + acc0[1]) + (acc0[2] + acc0[3]))
          + ((acc1[0] + acc1[1]) + (acc1[2] + acc1[3]));
  float q = ((acc0[0] * acc0[0] + acc0[1] * acc0[1]) + (acc0[2] * acc0[2] + acc0[3] * acc0[3]))
          + ((acc1[0] * acc1[0] + acc1[1] * acc1[1]) + (acc1[2] * acc1[2] + acc1[3] * acc1[3]));
  s = bfly32(bfly16(s));           // sum over the wave's 4 g-groups
  q = bfly32(bfly16(q));
  if (lane < 8)
    *reinterpret_cast<float2*>(&lnbuf[lane * 20 + grpoff + 2 * wl]) = make_float2(s, q);
  bar_lgkm();
  floatx4 p0 = *reinterpret_cast<const floatx4*>(&lnbuf[srow * 20 + grpoff + 0]);
  floatx4 p1 = *reinterpret_cast<const floatx4*>(&lnbuf[srow * 20 + grpoff + 4]);
  float S = (p0[0] + p0[2]) + (p1[0] + p1[2]);
  float Q = (p0[1] + p0[3]) + (p1[1] + p1[3]);
  float mean = S * 0.0078125f;
  float var = fmaf(Q, 0.0078125f, -mean * mean);
  float rs = __builtin_amdgcn_rsqf(var + 1e-5f);
  floatx4 acc = tsel ? acc1 : acc0;   // lane's half-tile
  float a0 = fmaf((acc[0] - mean) * rs, Asel[0], Esel[0]);
  float a1 = fmaf((acc[1] - mean) * rs, Asel[1], Esel[1]);
  float a2 = fmaf((acc[2] - mean) * rs, Asel[2], Esel[2]);
  float a3 = fmaf((acc[3] - mean) * rs, Asel[3], Esel[3]);
  float h0 = tanh_arg(a0);
  float h1 = tanh_arg(a1);
  float h2 = tanh_arg(a2);
  float h3 = tanh_arg(a3);
  *reinterpret_cast<uint2*>(&dst[srow * 168 + wofs]) =
      make_uint2(cvt_pk_bf16(h0, h1), cvt_pk_bf16(h2, h3));
  bar_lgkm();
}

// ---------------- fused scan+decode: waves 0-3 dynamics, waves 4-7 decoder(z_n).
// 8 rows/WG, grid 256, 512 threads. Weights in registers. No ztraj.
__global__ __launch_bounds__(512, 1) void rlp_fused6(
    const float* __restrict__ t,
    const u16* __restrict__ wdyn, const u16* __restrict__ wdec,
    const float* __restrict__ ctxg, const float* __restrict__ cew,
    const float* __restrict__ ceb, const float* __restrict__ z0w,
    const float* __restrict__ z0b,
    const float* __restrict__ db0, const float* __restrict__ db1,
    const float* __restrict__ db2, const float* __restrict__ db3,
    const float* __restrict__ dg0, const float* __restrict__ dbe0,
    const float* __restrict__ dg1, const float* __restrict__ dbe1,
    const float* __restrict__ dg2, const float* __restrict__ dbe2,
    const float* __restrict__ eb0, const float* __restrict__ eb1,
    const float* __restrict__ eb2, const float* __restrict__ eb3,
    const float* __restrict__ eg0, const float* __restrict__ ebe0,
    const float* __restrict__ eg1, const float* __restrict__ ebe1,
    const float* __restrict__ eg2, const float* __restrict__ ebe2,
    float* __restrict__ out) {
  __shared__ __align__(16) u16 xb[8 * 168];   // 0-63 z | 64-80 temb | 81-144 ctx | 145-167 zero
  __shared__ __align__(16) u16 hdA[8 * 168];
  __shared__ __align__(16) u16 hdB[8 * 168];
  __shared__ __align__(16) u16 heA[8 * 168];
  __shared__ __align__(16) u16 heB[8 * 168];
  __shared__ __align__(16) float lnS[8 * 20];  // [row][dyn 0-7 | dec 8-15]
  __shared__ __align__(16) float tl[8][260];
  __shared__ float ctxe[8][64];
  __shared__ float zbuf[8][64];

  const int tid = threadIdx.x;
  const int wv = tid >> 6;
  const int lane = tid & 63;
  const int rrow = lane & 15;
  const int g = lane >> 4;
  const int r8 = rrow & 7;
  const int wl = wv & 3;
  const bool isdyn = (wv < 4);
  const int grpoff = isdyn ? 0 : 8;
  const int gb = blockIdx.x * 8;
  const int tsel = (rrow >> 3) & 1;
  const int wofs = 32 * wl + tsel * 16 + 4 * g;   // this lane's finalize col base
  const int c0 = 32 * wl + 4 * g;

  const float* pb1 = isdyn ? db0 : eb0;
  const float* pg1 = isdyn ? dg0 : eg0;
  const float* pe1 = isdyn ? dbe0 : ebe0;
  const float* pb2 = isdyn ? db1 : eb1;
  const float* pg2 = isdyn ? dg1 : eg1;
  const float* pe2 = isdyn ? dbe1 : ebe1;
  const float* pb3 = isdyn ? db2 : eb2;
  const float* pg3 = isdyn ? dg2 : eg2;
  const float* pe3 = isdyn ? dbe2 : ebe2;

  const floatx4 b1t0 = *(const floatx4*)&pb1[c0];
  const floatx4 b1t1 = *(const floatx4*)&pb1[c0 + 16];
  const floatx4 b2t0 = *(const floatx4*)&pb2[c0];
  const floatx4 b2t1 = *(const floatx4*)&pb2[c0 + 16];
  const floatx4 b3t0 = *(const floatx4*)&pb3[c0];
  const floatx4 b3t1 = *(const floatx4*)&pb3[c0 + 16];
#define FOLD4(p) {p[wofs] * CC_, p[wofs + 1] * CC_, p[wofs + 2] * CC_, p[wofs + 3] * CC_}
  const floatx4 A1s = FOLD4(pg1), E1s = FOLD4(pe1);
  const floatx4 A2s = FOLD4(pg2), E2s = FOLD4(pe2);
  const floatx4 A3s = FOLD4(pg3), E3s = FOLD4(pe3);
#undef FOLD4
  floatx4 b4;
  if (isdyn) {
    b4 = *(const floatx4*)&db3[16 * wl + 4 * g];
  } else {
    int cb = 4 * g;
    b4[0] = (cb + 0 < 14) ? eb3[cb + 0] : 0.0f;
    b4[1] = (cb + 1 < 14) ? eb3[cb + 1] : 0.0f;
    b4[2] = (cb + 2 < 14) ? eb3[cb + 2] : 0.0f;
    b4[3] = (cb + 3 < 14) ? eb3[cb + 3] : 0.0f;
  }

  // ---- weight fragments: wA/wB = tiles 2wl / 2wl+1; slots [0-4]=L1, [5-8]=L2, [9-12]=L3.
  short8 wA[13], wB[13], w4[4];
  if (isdyn) {
#pragma unroll
    for (int ks = 0; ks < 5; ks++) {
      wA[ks] = *(const short8*)(wdyn + ((size_t)((2 * wl + 0) * 5 + ks) * 64 + lane) * 8);
      wB[ks] = *(const short8*)(wdyn + ((size_t)((2 * wl + 1) * 5 + ks) * 64 + lane) * 8);
    }
#pragma unroll
    for (int ks = 0; ks < 4; ks++) {
      wA[5 + ks] = *(const short8*)(wdyn + 20480 + ((size_t)((2 * wl + 0) * 4 + ks) * 64 + lane) * 8);
      wB[5 + ks] = *(const short8*)(wdyn + 20480 + ((size_t)((2 * wl + 1) * 4 + ks) * 64 + lane) * 8);
      wA[9 + ks] = *(const short8*)(wdyn + 36864 + ((size_t)((2 * wl + 0) * 4 + ks) * 64 + lane) * 8);
      wB[9 + ks] = *(const short8*)(wdyn + 36864 + ((size_t)((2 * wl + 1) * 4 + ks) * 64 + lane) * 8);
      w4[ks] = *(const short8*)(wdyn + 53248 + ((size_t)(wl * 4 + ks) * 64 + lane) * 8);
    }
  } else {
#pragma unroll
    for (int ks = 0; ks < 2; ks++) {
      wA[ks] = *(const short8*)(wdec + ((size_t)((2 * wl + 0) * 2 + ks) * 64 + lane) * 8);
      wB[ks] = *(const short8*)(wdec + ((size_t)((2 * wl + 1) * 2 + ks) * 64 + lane) * 8);
    }
#pragma unroll
    for (int ks = 0; ks < 4; ks++) {
      wA[5 + ks] = *(const short8*)(wdec + 8192 + ((size_t)((2 * wl + 0) * 4 + ks) * 64 + lane) * 8);
      wB[5 + ks] = *(const short8*)(wdec + 8192 + ((size_t)((2 * wl + 1) * 4 + ks) * 64 + lane) * 8);
      wA[9 + ks] = *(const short8*)(wdec + 24576 + ((size_t)((2 * wl + 0) * 4 + ks) * 64 + lane) * 8);
      wB[9 + ks] = *(const short8*)(wdec + 24576 + ((size_t)((2 * wl + 1) * 4 + ks) * 64 + lane) * 8);
      w4[ks] = *(const short8*)(wdec + 40960 + ((size_t)ks * 64 + lane) * 8);
    }
  }
  u16* h0 = isdyn ? hdA : heA;
  u16* h1 = isdyn ? hdB : heB;

  // ---- prologue: t -> LDS, zero xb, ctx encoder, z0 encoder, temb(0)
  for (int i = tid; i < 8 * 256; i += 512) {
    int r = i >> 8, c = i & 255;
    tl[r][c] = t[(size_t)(gb + r) * N_ + c];
  }
  for (int i = tid; i < 8 * 168 / 2; i += 512) reinterpret_cast<u32*>(&xb[0])[i] = 0;
  __syncthreads();
  {
    int b = tid >> 6, c = tid & 63;
    float s = ceb[c];
#pragma unroll
    for (int k = 0; k < 32; k++) s += ctxg[(size_t)(gb + b) * 32 + k] * cew[k * 64 + c];
    float v = tanh_fast(s);
    ctxe[b][c] = v;
    xb[b * 168 + 81 + c] = f2bf(v);
  }
  __syncthreads();
  {
    int b = tid >> 6, l = tid & 63;
    float s = z0b[l];
#pragma unroll 8
    for (int k = 0; k < 64; k++) s += ctxe[b][k] * z0w[k * 64 + l];
    zbuf[b][l] = tanh_fast(s);
  }
  if (tid < 136) {
    int b = tid / 17, j = tid - b * 17;
    xb[b * 168 + 64 + j] = f2bf(four_emb(tl[b][0], j));
  }
  __syncthreads();

  // z0 into dyn registers + xb
  float zr0, zr1, zr2, zr3;
  {
    const floatx4 zv = *(const floatx4*)&zbuf[r8][16 * wl + 4 * g];
    zr0 = zv[0]; zr1 = zv[1]; zr2 = zv[2]; zr3 = zv[3];
    if (isdyn && rrow < 8) {
      *reinterpret_cast<uint2*>(&xb[rrow * 168 + 16 * wl + 4 * g]) =
          make_uint2(cvt_pk_bf16(zr0, zr1), cvt_pk_bf16(zr2, zr3));
    }
  }
  __syncthreads();

  // dyn L1 static frags (cols 96-159: ctx + zero pad)
  short8 xs[2];
  xs[0] = *reinterpret_cast<const short8*>(&xb[r8 * 168 + 96 + g * 8]);
  xs[1] = *reinterpret_cast<const short8*>(&xb[r8 * 168 + 128 + g * 8]);

  // per-lane output row pointer (dec L4, wave 4), incremented per step
  float* po = out + ((size_t)(gb + r8) * N_) * 14 + 4 * g;

  for (int n = 0; n < N_; n++) {
    // phase A: L1 (dyn K=160: 3 dyn + 2 static frags; dec K=64: 2 frags of z in xb)
    if (isdyn)
      mlp_layer2<5, 3>(wA, wB, xs, b1t0, b1t1, A1s, E1s,
                       xb, h0, lnS, grpoff, wl, lane, tsel, wofs);
    else
      mlp_layer2<2, 2>(wA, wB, nullptr, b1t0, b1t1, A1s, E1s,
                       xb, h0, lnS, grpoff, wl, lane, tsel, wofs);
    // phase B: L2 ; phase C: L3
    mlp_layer2<4, 4>(wA + 5, wB + 5, nullptr, b2t0, b2t1, A2s, E2s,
                     h0, h1, lnS, grpoff, wl, lane, tsel, wofs);
    mlp_layer2<4, 4>(wA + 9, wB + 9, nullptr, b3t0, b3t1, A3s, E3s,
                     h1, h0, lnS, grpoff, wl, lane, tsel, wofs);
    // phase D
    if (isdyn) {
      if (n < N_ - 1) {
        short8 xf4[4];
#pragma unroll
        for (int ks = 0; ks < 4; ks++)
          xf4[ks] = *reinterpret_cast<const short8*>(&h0[r8 * 168 + ks * 32 + g * 8]);
        floatx4 da = b4;
        __builtin_amdgcn_s_setprio(1);
#pragma unroll
        for (int ks = 0; ks < 4; ks++)
          da = __builtin_amdgcn_mfma_f32_16x16x32_bf16(w4[ks], xf4[ks], da, 0, 0, 0);
        __builtin_amdgcn_s_setprio(0);
        float dt = tl[r8][n + 1] - tl[r8][n];
        zr0 += dt * da[0]; zr1 += dt * da[1]; zr2 += dt * da[2]; zr3 += dt * da[3];
        if (rrow < 8) {
          *reinterpret_cast<uint2*>(&xb[rrow * 168 + 16 * wl + 4 * g]) =
              make_uint2(cvt_pk_bf16(zr0, zr1), cvt_pk_bf16(zr2, zr3));
        }
      }
    } else if (wv == 4) {
      // decoder L4: 14 output cols for the 8 rows, step n
      short8 xf4[4];
#pragma unroll
      for (int ks = 0; ks < 4; ks++)
        xf4[ks] = *reinterpret_cast<const short8*>(&h0[r8 * 168 + ks * 32 + g * 8]);
      floatx4 da = b4;
      __builtin_amdgcn_s_setprio(1);
#pragma unroll
      for (int ks = 0; ks < 4; ks++)
        da = __builtin_amdgcn_mfma_f32_16x16x32_bf16(w4[ks], xf4[ks], da, 0, 0, 0);
      __builtin_amdgcn_s_setprio(0);
      if (rrow < 8) {
        *reinterpret_cast<float2*>(po) = make_float2(da[0], da[1]);
        if (g < 3) *reinterpret_cast<float2*>(po + 2) = make_float2(da[2], da[3]);
      }
    } else {
      // waves 5-7: Fourier embedding for step n+1
      int t2 = tid - 320;
      if (t2 < 136 && n < N_ - 2) {
        int b = t2 / 17, j = t2 - b * 17;
        xb[b * 168 + 64 + j] = f2bf(four_emb(tl[b][n + 1], j));
      }
    }
    po += 14;
    bar_lgkm();
  }
}

extern "C" void kernel_launch(void* const* d_in, const int* in_sizes, int n_in,
                              void* d_out, int out_size, void* d_ws, size_t ws_size,
                              hipStream_t stream) {
  const float* t = (const float*)d_in[0];
  const float* ctx = (const float*)d_in[1];
  const float* ce_w = (const float*)d_in[2];
  const float* ce_b = (const float*)d_in[3];
  const float* z0_w = (const float*)d_in[4];
  const float* z0_b = (const float*)d_in[5];
  const float* dw0 = (const float*)d_in[6];
  const float* db0 = (const float*)d_in[7];
  const float* dw1 = (const float*)d_in[8];
  const float* db1 = (const float*)d_in[9];
  const float* dw2 = (const float*)d_in[10];
  const float* db2 = (const float*)d_in[11];
  const float* dw3 = (const float*)d_in[12];
  const float* db3 = (const float*)d_in[13];
  const float* dg0 = (const float*)d_in[14];
  const float* dbe0 = (const float*)d_in[15];
  const float* dg1 = (const float*)d_in[16];
  const float* dbe1 = (const float*)d_in[17];
  const float* dg2 = (const float*)d_in[18];
  const float* dbe2 = (const float*)d_in[19];
  const float* ew0 = (const float*)d_in[20];
  const float* eb0 = (const float*)d_in[21];
  const float* ew1 = (const float*)d_in[22];
  const float* eb1 = (const float*)d_in[23];
  const float* ew2 = (const float*)d_in[24];
  const float* eb2 = (const float*)d_in[25];
  const float* ew3 = (const float*)d_in[26];
  const float* eb3 = (const float*)d_in[27];
  const float* eg0 = (const float*)d_in[28];
  const float* ebe0 = (const float*)d_in[29];
  const float* eg1 = (const float*)d_in[30];
  const float* ebe1 = (const float*)d_in[31];
  const float* eg2 = (const float*)d_in[32];
  const float* ebe2 = (const float*)d_in[33];
  float* out = (float*)d_out;

  char* ws = (char*)d_ws;
  u16* wdyn = (u16*)(ws + 0);        // 61440 elems = 122880 B
  u16* wdec = (u16*)(ws + 122880);   // 43008 elems =  86016 B

  rlp_pack_all<<<408, 256, 0, stream>>>(dw0, dw1, dw2, dw3, ew0, ew1, ew2, ew3, wdyn, wdec);

  rlp_fused6<<<B_ / 8, 512, 0, stream>>>(t, wdyn, wdec, ctx, ce_w, ce_b, z0_w, z0_b,
      db0, db1, db2, db3, dg0, dbe0, dg1, dbe1, dg2, dbe2,
      eb0, eb1, eb2, eb3, eg0, ebe0, eg1, ebe1, eg2, ebe2, out);
}

// Round 15
// 455.149 us; speedup vs baseline: 1.6446x; 1.0193x over previous
//
#include <hip/hip_runtime.h>
#include <cstdint>
#include <cstddef>

#define B_ 2048
#define N_ 256

typedef unsigned short u16;
typedef unsigned int u32;
typedef __attribute__((ext_vector_type(8))) short short8;
typedef __attribute__((ext_vector_type(4))) float floatx4;

__device__ __forceinline__ u16 f2bf(float f) {
  union { float f; unsigned u; } v; v.f = f;
  unsigned u = v.u;
  return (u16)((u + 0x7FFFu + ((u >> 16) & 1u)) >> 16);
}
__device__ __forceinline__ u32 cvt_pk_bf16(float a, float b) {
  u32 r;
  asm("v_cvt_pk_bf16_f32 %0, %1, %2" : "=v"(r) : "v"(a), "v"(b));
  return r;
}
// VALU butterfly adds over lane^16 / lane^32 (proven bit-exact R8)
__device__ __forceinline__ float bfly16(float x) {
  auto r = __builtin_amdgcn_permlane16_swap(__float_as_int(x), __float_as_int(x), false, false);
  return __int_as_float(r[0]) + __int_as_float(r[1]);
}
__device__ __forceinline__ float bfly32(float x) {
  auto r = __builtin_amdgcn_permlane32_swap(__float_as_int(x), __float_as_int(x), false, false);
  return __int_as_float(r[0]) + __int_as_float(r[1]);
}
#define CC_ 2.885390081777927f  /* 2*log2(e) */
__device__ __forceinline__ float tanh_fast(float x) {
  float u = __builtin_amdgcn_exp2f(x * CC_);
  return fmaf(__builtin_amdgcn_rcpf(u + 1.0f), -2.0f, 1.0f);
}
__device__ __forceinline__ float tanh_arg(float x) {  // tanh(y) where x = y*CC_ already
  float u = __builtin_amdgcn_exp2f(x);
  return fmaf(__builtin_amdgcn_rcpf(u + 1.0f), -2.0f, 1.0f);
}
__device__ __forceinline__ float four_emb(float tv, int j) {
  if (j == 0) return tv;
  int jj = (j <= 8) ? j : j - 8;
  float sc = __int_as_float((jj + 125) << 23);  // 2^(jj-2)
  float r = __builtin_amdgcn_fractf(tv * sc);
  return (j <= 8) ? __builtin_amdgcn_sinf(r) : __builtin_amdgcn_cosf(r);
}
// LDS-only barrier (no vmcnt drain)
__device__ __forceinline__ void bar_lgkm() {
  asm volatile("s_waitcnt lgkmcnt(0)" ::: "memory");
  __builtin_amdgcn_s_barrier();
}

// ---------------- combined weight packer (one launch).
__global__ void rlp_pack_all(const float* __restrict__ dw0, const float* __restrict__ dw1,
                             const float* __restrict__ dw2, const float* __restrict__ dw3,
                             const float* __restrict__ ew0, const float* __restrict__ ew1,
                             const float* __restrict__ ew2, const float* __restrict__ ew3,
                             u16* __restrict__ wdyn, u16* __restrict__ wdec) {
  int e = blockIdx.x * blockDim.x + threadIdx.x;
  const float* W; int K, Nc, ks, base; u16* dst;
  if (e < 20480)       { W = dw0; K = 145; Nc = 128; ks = 5; dst = wdyn;         base = 0; }
  else if (e < 36864)  { W = dw1; K = 128; Nc = 128; ks = 4; dst = wdyn + 20480; base = 20480; }
  else if (e < 53248)  { W = dw2; K = 128; Nc = 128; ks = 4; dst = wdyn + 36864; base = 36864; }
  else if (e < 61440)  { W = dw3; K = 128; Nc = 64;  ks = 4; dst = wdyn + 53248; base = 53248; }
  else if (e < 69632)  { W = ew0; K = 64;  Nc = 128; ks = 2; dst = wdec;         base = 61440; }
  else if (e < 86016)  { W = ew1; K = 128; Nc = 128; ks = 4; dst = wdec + 8192;  base = 69632; }
  else if (e < 102400) { W = ew2; K = 128; Nc = 128; ks = 4; dst = wdec + 24576; base = 86016; }
  else if (e < 104448) { W = ew3; K = 128; Nc = 14;  ks = 4; dst = wdec + 40960; base = 102400; }
  else return;
  int el = e - base;
  int j = el & 7;
  int lane = (el >> 3) & 63;
  int tt = el >> 9;
  int ksi = tt % ks;
  int nt = tt / ks;
  int col = nt * 16 + (lane & 15);
  int k = ksi * 32 + ((lane >> 4) << 3) + j;
  float v = 0.0f;
  if (k < K && col < Nc) v = W[k * Nc + col];
  dst[el] = f2bf(v);
}

// ---------------- one hidden layer, 2 col-tiles per wave.
// Lane-split finalize: lanes rrow<8 finalize tile0, rrow>=8 finalize tile1.
// lowprio = wave's resting priority (dyn recurrence waves rest at 1).
template <int KS>
__device__ __forceinline__ void mlp_layer2(
    const short8* wT0, const short8* wT1,
    floatx4 bv0, floatx4 bv1,
    floatx4 Asel, floatx4 Esel,       // per-lane consts at cols [wofs..wofs+3]
    const u16* src, u16* dst, float* lnbuf,
    int grpoff, int wl, int lane, int tsel, int wofs, int lowprio) {
  const int rrow = lane & 15;
  const int g = lane >> 4;
  const int srow = rrow & 7;
  short8 xf[KS];
#pragma unroll
  for (int ks = 0; ks < KS; ks++)
    xf[ks] = *reinterpret_cast<const short8*>(&src[srow * 168 + ks * 32 + g * 8]);
  floatx4 acc0 = bv0, acc1 = bv1;
  __builtin_amdgcn_s_setprio(1);
#pragma unroll
  for (int ks = 0; ks < KS; ks++) {
    acc0 = __builtin_amdgcn_mfma_f32_16x16x32_bf16(wT0[ks], xf[ks], acc0, 0, 0, 0);
    acc1 = __builtin_amdgcn_mfma_f32_16x16x32_bf16(wT1[ks], xf[ks], acc1, 0, 0, 0);
  }
  __builtin_amdgcn_s_setprio(0);
  if (lowprio) __builtin_amdgcn_s_setprio(1);
  float s = ((acc0[0] + acc0[1]) + (acc0[2] + acc0[3]))
          + ((acc1[0] + acc1[1]) + (acc1[2] + acc1[3]));
  float q = ((acc0[0] * acc0[0] + acc0[1] * acc0[1]) + (acc0[2] * acc0[2] + acc0[3] * acc0[3]))
          + ((acc1[0] * acc1[0] + acc1[1] * acc1[1]) + (acc1[2] * acc1[2] + acc1[3] * acc1[3]));
  s = bfly32(bfly16(s));           // sum over the wave's 4 g-groups
  q = bfly32(bfly16(q));
  if (lane < 8)
    *reinterpret_cast<float2*>(&lnbuf[lane * 20 + grpoff + 2 * wl]) = make_float2(s, q);
  bar_lgkm();
  floatx4 p0 = *reinterpret_cast<const floatx4*>(&lnbuf[srow * 20 + grpoff + 0]);
  floatx4 p1 = *reinterpret_cast<const floatx4*>(&lnbuf[srow * 20 + grpoff + 4]);
  float S = (p0[0] + p0[2]) + (p1[0] + p1[2]);
  float Q = (p0[1] + p0[3]) + (p1[1] + p1[3]);
  float mean = S * 0.0078125f;
  float var = fmaf(Q, 0.0078125f, -mean * mean);
  float rs = __builtin_amdgcn_rsqf(var + 1e-5f);
  floatx4 acc = tsel ? acc1 : acc0;   // lane's half-tile
  float a0 = fmaf((acc[0] - mean) * rs, Asel[0], Esel[0]);
  float a1 = fmaf((acc[1] - mean) * rs, Asel[1], Esel[1]);
  float a2 = fmaf((acc[2] - mean) * rs, Asel[2], Esel[2]);
  float a3 = fmaf((acc[3] - mean) * rs, Asel[3], Esel[3]);
  float h0 = tanh_arg(a0);
  float h1 = tanh_arg(a1);
  float h2 = tanh_arg(a2);
  float h3 = tanh_arg(a3);
  *reinterpret_cast<uint2*>(&dst[srow * 168 + wofs]) =
      make_uint2(cvt_pk_bf16(h0, h1), cvt_pk_bf16(h2, h3));
  bar_lgkm();
}

// ---------------- fused scan+decode: waves 0-3 dynamics, waves 4-7 decoder(z_n).
// 8 rows/WG, grid 256, 512 threads. Weights in registers. No ztraj.
// Dyn L1 static part (ctx cols 96-159) folded into a loop-invariant accumulator.
__global__ __launch_bounds__(512, 1) void rlp_fused7(
    const float* __restrict__ t,
    const u16* __restrict__ wdyn, const u16* __restrict__ wdec,
    const float* __restrict__ ctxg, const float* __restrict__ cew,
    const float* __restrict__ ceb, const float* __restrict__ z0w,
    const float* __restrict__ z0b,
    const float* __restrict__ db0, const float* __restrict__ db1,
    const float* __restrict__ db2, const float* __restrict__ db3,
    const float* __restrict__ dg0, const float* __restrict__ dbe0,
    const float* __restrict__ dg1, const float* __restrict__ dbe1,
    const float* __restrict__ dg2, const float* __restrict__ dbe2,
    const float* __restrict__ eb0, const float* __restrict__ eb1,
    const float* __restrict__ eb2, const float* __restrict__ eb3,
    const float* __restrict__ eg0, const float* __restrict__ ebe0,
    const float* __restrict__ eg1, const float* __restrict__ ebe1,
    const float* __restrict__ eg2, const float* __restrict__ ebe2,
    float* __restrict__ out) {
  __shared__ __align__(16) u16 xb[8 * 168];   // 0-63 z | 64-80 temb | 81-144 ctx | 145-167 zero
  __shared__ __align__(16) u16 hdA[8 * 168];
  __shared__ __align__(16) u16 hdB[8 * 168];
  __shared__ __align__(16) u16 heA[8 * 168];
  __shared__ __align__(16) u16 heB[8 * 168];
  __shared__ __align__(16) float lnS[8 * 20];  // [row][dyn 0-7 | dec 8-15]
  __shared__ __align__(16) float tl[8][260];
  __shared__ float ctxe[8][64];
  __shared__ float zbuf[8][64];

  const int tid = threadIdx.x;
  const int wv = tid >> 6;
  const int lane = tid & 63;
  const int rrow = lane & 15;
  const int g = lane >> 4;
  const int r8 = rrow & 7;
  const int wl = wv & 3;
  const bool isdyn = (wv < 4);
  const int lowprio = isdyn ? 1 : 0;
  const int grpoff = isdyn ? 0 : 8;
  const int gb = blockIdx.x * 8;
  const int tsel = (rrow >> 3) & 1;
  const int wofs = 32 * wl + tsel * 16 + 4 * g;   // this lane's finalize col base
  const int c0 = 32 * wl + 4 * g;

  const float* pb1 = isdyn ? db0 : eb0;
  const float* pg1 = isdyn ? dg0 : eg0;
  const float* pe1 = isdyn ? dbe0 : ebe0;
  const float* pb2 = isdyn ? db1 : eb1;
  const float* pg2 = isdyn ? dg1 : eg1;
  const float* pe2 = isdyn ? dbe1 : ebe1;
  const float* pb3 = isdyn ? db2 : eb2;
  const float* pg3 = isdyn ? dg2 : eg2;
  const float* pe3 = isdyn ? dbe2 : ebe2;

  const floatx4 b1t0 = *(const floatx4*)&pb1[c0];
  const floatx4 b1t1 = *(const floatx4*)&pb1[c0 + 16];
  const floatx4 b2t0 = *(const floatx4*)&pb2[c0];
  const floatx4 b2t1 = *(const floatx4*)&pb2[c0 + 16];
  const floatx4 b3t0 = *(const floatx4*)&pb3[c0];
  const floatx4 b3t1 = *(const floatx4*)&pb3[c0 + 16];
#define FOLD4(p) {p[wofs] * CC_, p[wofs + 1] * CC_, p[wofs + 2] * CC_, p[wofs + 3] * CC_}
  const floatx4 A1s = FOLD4(pg1), E1s = FOLD4(pe1);
  const floatx4 A2s = FOLD4(pg2), E2s = FOLD4(pe2);
  const floatx4 A3s = FOLD4(pg3), E3s = FOLD4(pe3);
#undef FOLD4
  floatx4 b4;
  if (isdyn) {
    b4 = *(const floatx4*)&db3[16 * wl + 4 * g];
  } else {
    int cb = 4 * g;
    b4[0] = (cb + 0 < 14) ? eb3[cb + 0] : 0.0f;
    b4[1] = (cb + 1 < 14) ? eb3[cb + 1] : 0.0f;
    b4[2] = (cb + 2 < 14) ? eb3[cb + 2] : 0.0f;
    b4[3] = (cb + 3 < 14) ? eb3[cb + 3] : 0.0f;
  }

  // ---- weight fragments: wA/wB = tiles 2wl / 2wl+1; slots [0-4]=L1, [5-8]=L2, [9-12]=L3.
  short8 wA[13], wB[13], w4[4];
  if (isdyn) {
#pragma unroll
    for (int ks = 0; ks < 5; ks++) {
      wA[ks] = *(const short8*)(wdyn + ((size_t)((2 * wl + 0) * 5 + ks) * 64 + lane) * 8);
      wB[ks] = *(const short8*)(wdyn + ((size_t)((2 * wl + 1) * 5 + ks) * 64 + lane) * 8);
    }
#pragma unroll
    for (int ks = 0; ks < 4; ks++) {
      wA[5 + ks] = *(const short8*)(wdyn + 20480 + ((size_t)((2 * wl + 0) * 4 + ks) * 64 + lane) * 8);
      wB[5 + ks] = *(const short8*)(wdyn + 20480 + ((size_t)((2 * wl + 1) * 4 + ks) * 64 + lane) * 8);
      wA[9 + ks] = *(const short8*)(wdyn + 36864 + ((size_t)((2 * wl + 0) * 4 + ks) * 64 + lane) * 8);
      wB[9 + ks] = *(const short8*)(wdyn + 36864 + ((size_t)((2 * wl + 1) * 4 + ks) * 64 + lane) * 8);
      w4[ks] = *(const short8*)(wdyn + 53248 + ((size_t)(wl * 4 + ks) * 64 + lane) * 8);
    }
  } else {
#pragma unroll
    for (int ks = 0; ks < 2; ks++) {
      wA[ks] = *(const short8*)(wdec + ((size_t)((2 * wl + 0) * 2 + ks) * 64 + lane) * 8);
      wB[ks] = *(const short8*)(wdec + ((size_t)((2 * wl + 1) * 2 + ks) * 64 + lane) * 8);
    }
    wA[2] = wA[0]; wB[2] = wB[0]; wA[3] = wA[0]; wB[3] = wB[0]; wA[4] = wA[0]; wB[4] = wB[0];
#pragma unroll
    for (int ks = 0; ks < 4; ks++) {
      wA[5 + ks] = *(const short8*)(wdec + 8192 + ((size_t)((2 * wl + 0) * 4 + ks) * 64 + lane) * 8);
      wB[5 + ks] = *(const short8*)(wdec + 8192 + ((size_t)((2 * wl + 1) * 4 + ks) * 64 + lane) * 8);
      wA[9 + ks] = *(const short8*)(wdec + 24576 + ((size_t)((2 * wl + 0) * 4 + ks) * 64 + lane) * 8);
      wB[9 + ks] = *(const short8*)(wdec + 24576 + ((size_t)((2 * wl + 1) * 4 + ks) * 64 + lane) * 8);
      w4[ks] = *(const short8*)(wdec + 40960 + ((size_t)ks * 64 + lane) * 8);
    }
  }
  u16* h0 = isdyn ? hdA : heA;
  u16* h1 = isdyn ? hdB : heB;

  // ---- prologue: t -> LDS, zero xb, ctx encoder, z0 encoder, temb(0)
  for (int i = tid; i < 8 * 256; i += 512) {
    int r = i >> 8, c = i & 255;
    tl[r][c] = t[(size_t)(gb + r) * N_ + c];
  }
  for (int i = tid; i < 8 * 168 / 2; i += 512) reinterpret_cast<u32*>(&xb[0])[i] = 0;
  __syncthreads();
  {
    int b = tid >> 6, c = tid & 63;
    float s = ceb[c];
#pragma unroll
    for (int k = 0; k < 32; k++) s += ctxg[(size_t)(gb + b) * 32 + k] * cew[k * 64 + c];
    float v = tanh_fast(s);
    ctxe[b][c] = v;
    xb[b * 168 + 81 + c] = f2bf(v);
  }
  __syncthreads();
  {
    int b = tid >> 6, l = tid & 63;
    float s = z0b[l];
#pragma unroll 8
    for (int k = 0; k < 64; k++) s += ctxe[b][k] * z0w[k * 64 + l];
    zbuf[b][l] = tanh_fast(s);
  }
  if (tid < 136) {
    int b = tid / 17, j = tid - b * 17;
    xb[b * 168 + 64 + j] = f2bf(four_emb(tl[b][0], j));
  }
  __syncthreads();

  // z0 into dyn registers + xb
  float zr0, zr1, zr2, zr3;
  {
    const floatx4 zv = *(const floatx4*)&zbuf[r8][16 * wl + 4 * g];
    zr0 = zv[0]; zr1 = zv[1]; zr2 = zv[2]; zr3 = zv[3];
    if (isdyn && rrow < 8) {
      *reinterpret_cast<uint2*>(&xb[rrow * 168 + 16 * wl + 4 * g]) =
          make_uint2(cvt_pk_bf16(zr0, zr1), cvt_pk_bf16(zr2, zr3));
    }
  }
  __syncthreads();

  // dyn L1 loop-invariant accumulator: b1 + W(ks=3,4) * static ctx frags (cols 96-159)
  floatx4 accL1t0 = b1t0, accL1t1 = b1t1;
  if (isdyn) {
    short8 xs0 = *reinterpret_cast<const short8*>(&xb[r8 * 168 + 96 + g * 8]);
    short8 xs1 = *reinterpret_cast<const short8*>(&xb[r8 * 168 + 128 + g * 8]);
    accL1t0 = __builtin_amdgcn_mfma_f32_16x16x32_bf16(wA[3], xs0, accL1t0, 0, 0, 0);
    accL1t0 = __builtin_amdgcn_mfma_f32_16x16x32_bf16(wA[4], xs1, accL1t0, 0, 0, 0);
    accL1t1 = __builtin_amdgcn_mfma_f32_16x16x32_bf16(wB[3], xs0, accL1t1, 0, 0, 0);
    accL1t1 = __builtin_amdgcn_mfma_f32_16x16x32_bf16(wB[4], xs1, accL1t1, 0, 0, 0);
    __builtin_amdgcn_s_setprio(1);   // recurrence waves rest at priority 1
  }

  // per-lane output row pointer (dec L4, wave 4), incremented per step
  float* po = out + ((size_t)(gb + r8) * N_) * 14 + 4 * g;

  for (int n = 0; n < N_; n++) {
    // phase A: L1 (dyn: 3 dynamic frags on top of invariant acc; dec: 2 frags of z)
    if (isdyn)
      mlp_layer2<3>(wA, wB, accL1t0, accL1t1, A1s, E1s,
                    xb, h0, lnS, grpoff, wl, lane, tsel, wofs, lowprio);
    else
      mlp_layer2<2>(wA, wB, b1t0, b1t1, A1s, E1s,
                    xb, h0, lnS, grpoff, wl, lane, tsel, wofs, lowprio);
    // phase B: L2 ; phase C: L3
    mlp_layer2<4>(wA + 5, wB + 5, b2t0, b2t1, A2s, E2s,
                  h0, h1, lnS, grpoff, wl, lane, tsel, wofs, lowprio);
    mlp_layer2<4>(wA + 9, wB + 9, b3t0, b3t1, A3s, E3s,
                  h1, h0, lnS, grpoff, wl, lane, tsel, wofs, lowprio);
    // phase D
    if (isdyn) {
      if (n < N_ - 1) {
        short8 xf4[4];
#pragma unroll
        for (int ks = 0; ks < 4; ks++)
          xf4[ks] = *reinterpret_cast<const short8*>(&h0[r8 * 168 + ks * 32 + g * 8]);
        floatx4 da = b4;
#pragma unroll
        for (int ks = 0; ks < 4; ks++)
          da = __builtin_amdgcn_mfma_f32_16x16x32_bf16(w4[ks], xf4[ks], da, 0, 0, 0);
        float dt = tl[r8][n + 1] - tl[r8][n];
        zr0 += dt * da[0]; zr1 += dt * da[1]; zr2 += dt * da[2]; zr3 += dt * da[3];
        if (rrow < 8) {
          *reinterpret_cast<uint2*>(&xb[rrow * 168 + 16 * wl + 4 * g]) =
              make_uint2(cvt_pk_bf16(zr0, zr1), cvt_pk_bf16(zr2, zr3));
        }
      }
    } else if (wv == 4) {
      // decoder L4: 14 output cols for the 8 rows, step n
      short8 xf4[4];
#pragma unroll
      for (int ks = 0; ks < 4; ks++)
        xf4[ks] = *reinterpret_cast<const short8*>(&h0[r8 * 168 + ks * 32 + g * 8]);
      floatx4 da = b4;
      __builtin_amdgcn_s_setprio(1);
#pragma unroll
      for (int ks = 0; ks < 4; ks++)
        da = __builtin_amdgcn_mfma_f32_16x16x32_bf16(w4[ks], xf4[ks], da, 0, 0, 0);
      __builtin_amdgcn_s_setprio(0);
      if (rrow < 8) {
        *reinterpret_cast<float2*>(po) = make_float2(da[0], da[1]);
        if (g < 3) *reinterpret_cast<float2*>(po + 2) = make_float2(da[2], da[3]);
      }
    } else {
      // waves 5-7: Fourier embedding for step n+1
      int t2 = tid - 320;
      if (t2 < 136 && n < N_ - 2) {
        int b = t2 / 17, j = t2 - b * 17;
        xb[b * 168 + 64 + j] = f2bf(four_emb(tl[b][n + 1], j));
      }
    }
    po += 14;
    bar_lgkm();
  }
}

extern "C" void kernel_launch(void* const* d_in, const int* in_sizes, int n_in,
                              void* d_out, int out_size, void* d_ws, size_t ws_size,
                              hipStream_t stream) {
  const float* t = (const float*)d_in[0];
  const float* ctx = (const float*)d_in[1];
  const float* ce_w = (const float*)d_in[2];
  const float* ce_b = (const float*)d_in[3];
  const float* z0_w = (const float*)d_in[4];
  const float* z0_b = (const float*)d_in[5];
  const float* dw0 = (const float*)d_in[6];
  const float* db0 = (const float*)d_in[7];
  const float* dw1 = (const float*)d_in[8];
  const float* db1 = (const float*)d_in[9];
  const float* dw2 = (const float*)d_in[10];
  const float* db2 = (const float*)d_in[11];
  const float* dw3 = (const float*)d_in[12];
  const float* db3 = (const float*)d_in[13];
  const float* dg0 = (const float*)d_in[14];
  const float* dbe0 = (const float*)d_in[15];
  const float* dg1 = (const float*)d_in[16];
  const float* dbe1 = (const float*)d_in[17];
  const float* dg2 = (const float*)d_in[18];
  const float* dbe2 = (const float*)d_in[19];
  const float* ew0 = (const float*)d_in[20];
  const float* eb0 = (const float*)d_in[21];
  const float* ew1 = (const float*)d_in[22];
  const float* eb1 = (const float*)d_in[23];
  const float* ew2 = (const float*)d_in[24];
  const float* eb2 = (const float*)d_in[25];
  const float* ew3 = (const float*)d_in[26];
  const float* eb3 = (const float*)d_in[27];
  const float* eg0 = (const float*)d_in[28];
  const float* ebe0 = (const float*)d_in[29];
  const float* eg1 = (const float*)d_in[30];
  const float* ebe1 = (const float*)d_in[31];
  const float* eg2 = (const float*)d_in[32];
  const float* ebe2 = (const float*)d_in[33];
  float* out = (float*)d_out;

  char* ws = (char*)d_ws;
  u16* wdyn = (u16*)(ws + 0);        // 61440 elems = 122880 B
  u16* wdec = (u16*)(ws + 122880);   // 43008 elems =  86016 B

  rlp_pack_all<<<408, 256, 0, stream>>>(dw0, dw1, dw2, dw3, ew0, ew1, ew2, ew3, wdyn, wdec);

  rlp_fused7<<<B_ / 8, 512, 0, stream>>>(t, wdyn, wdec, ctx, ce_w, ce_b, z0_w, z0_b,
      db0, db1, db2, db3, dg0, dbe0, dg1, dbe1, dg2, dbe2,
      eb0, eb1, eb2, eb3, eg0, ebe0, eg1, ebe1, eg2, ebe2, out);
}